// Round 5
// baseline (5915.120 us; speedup 1.0000x reference)
//
#include <hip/hip_runtime.h>
#include <cstdint>

// CRF2 forward: B=64, S=1024, K=64.
// i-decomposition: 64 WGs x 512 thr; WG i owns tag-column i for ALL batches.
// M[b,i,j] = sum_k A[b,k,i]*T[k,i,j] over batches b is a GEMM -> MFMA 16x16x32 f16
// with K extended to 128: A128=[A_hi;A_lo], B128=[T;T] (hi/lo f16 state split).
// Waves are independent dataflow agents: 4 planes (mt = b-group of 16 batches),
// each plane = 128 waves in tag-lockstep. Exchange via 2-slot parity-tagged
// words in LLC (agent scope). ZERO LDS, ZERO barriers in the main loop.
// wsA word layout: idx = (((slot*64 + j)*4 + mt)*64 + k)*16 + br
//   producer i writes (j, mt, k=i, br=b&15); consumer j reads all k for its rows.

typedef _Float16 f16;
typedef _Float16 f16x8 __attribute__((ext_vector_type(8)));
typedef float f32x4 __attribute__((ext_vector_type(4)));
typedef unsigned int u32;
typedef unsigned short u16;
typedef u32 u32x4v __attribute__((ext_vector_type(4)));

static __device__ inline void st_agent(u32* p, u32 v) {
  __hip_atomic_store(p, v, __ATOMIC_RELAXED, __HIP_MEMORY_SCOPE_AGENT);
}
static __device__ inline u32 ld_agent(const u32* p) {
  return __hip_atomic_load(p, __ATOMIC_RELAXED, __HIP_MEMORY_SCOPE_AGENT);
}

static __device__ inline float fdot2_(u32 a, u32 b, float c) {
  typedef _Float16 f16x2 __attribute__((ext_vector_type(2)));
  f16x2 av = __builtin_bit_cast(f16x2, a);
  f16x2 bv = __builtin_bit_cast(f16x2, b);
#if __has_builtin(__builtin_amdgcn_fdot2)
  return __builtin_amdgcn_fdot2(av, bv, c, false);
#else
  c = __builtin_fmaf((float)av[0], (float)bv[0], c);
  return __builtin_fmaf((float)av[1], (float)bv[1], c);
#endif
}

// word: hi f16 | (lo f16 with bit0 = generation parity) << 16
static __device__ inline u32 pack_tag(float v, u32 q) {
  f16 h = (f16)v;
  f16 l = (f16)(v - (float)h);
  u32 hb = (u32)__builtin_bit_cast(u16, h);
  u32 lb = (u32)__builtin_bit_cast(u16, l);
  lb = (lb & 0xFFFEu) | q;
  return hb | (lb << 16);
}

static __device__ inline f16x8 mk8(u32 a, u32 b, u32 c, u32 d) {
  u32x4v t = {a, b, c, d};
  return __builtin_bit_cast(f16x8, t);
}

// ---- prep: init wsA slot parity tags; Y[:,0,:] = X[:,0,:] ----
__global__ void prep_kernel(const float* __restrict__ X, u32* __restrict__ wsA,
                            float* __restrict__ Y) {
  int idx = blockIdx.x * 256 + threadIdx.x;   // 0..524287 (2 slots x 262144 words)
  int slot = idx >> 18;
  // slot1 first written at t=1 (q=0) -> init tag 1; slot0 at t=2 (q=1) -> init 0
  wsA[idx] = (slot == 0) ? 0u : 0x00010000u;
  if (idx < 4096) {
    int b = idx >> 6, j = idx & 63;
    Y[b * 65536 + j] = X[b * 65536 + j];
  }
}

// ---- main kernel: 64 WGs x 512 threads, no LDS, no barriers ----
__global__ __launch_bounds__(512, 1)
void crf_kernel(const float* __restrict__ X, const float* __restrict__ Tg,
                u32* __restrict__ wsA, float* __restrict__ Y) {
  const int i_me = blockIdx.x;      // owned tag column 0..63
  const int tid  = threadIdx.x;
  const int w    = tid >> 6;        // wave 0..7
  const int l    = tid & 63;
  const int lq   = l >> 4;          // quarter 0..3
  const int ln   = l & 15;
  const int mt   = w >> 1;          // batch-group (plane) 0..3
  const int ntb  = (w & 1) * 2;     // first n-tile (j-group)

  // B fragments: B128[k',n] with kt0/kt1 = T rows 0..63 (kt2=kt0, kt3=kt1).
  // lane: col n = l&15 -> j = (ntb+s)*16+ln ; k = kb*32 + lq*8 + e
  u32 Bf[2][2][4];   // [s (n-tile)][kb][reg]
#pragma unroll
  for (int s = 0; s < 2; ++s)
#pragma unroll
    for (int kb = 0; kb < 2; ++kb)
#pragma unroll
      for (int r = 0; r < 4; ++r) {
        int k0 = kb * 32 + lq * 8 + 2 * r;
        int j  = (ntb + s) * 16 + ln;
        f16 a = (f16)Tg[k0 * 4096 + i_me * 64 + j];
        f16 b = (f16)Tg[(k0 + 1) * 4096 + i_me * 64 + j];
        Bf[s][kb][r] = (u32)__builtin_bit_cast(u16, a) |
                       ((u32)__builtin_bit_cast(u16, b) << 16);
      }

  // A fragments for t=0 state: A0[b,k] = x0[b]/64 (constant over k).
  // A-frag lane: row m = l&15 -> b = mt*16+ln ; k = lq*8+e
  u32 Af[4][4];      // [kt][reg]
  {
    float v = X[(mt * 16 + ln) * 65536 + i_me] * 0.015625f;
    f16 h = (f16)v; f16 lo = (f16)(v - (float)h);
    u32 hw = (u32)__builtin_bit_cast(u16, h);  hw |= hw << 16;
    u32 lw = (u32)__builtin_bit_cast(u16, lo); lw &= 0xFFFEu; lw |= lw << 16;
#pragma unroll
    for (int r = 0; r < 4; ++r) { Af[0][r] = hw; Af[1][r] = hw; Af[2][r] = lw; Af[3][r] = lw; }
  }

  // consumer word index (in-slot), e adds 16 words, W1 adds 512:
  const int cidx0 = ((i_me * 4 + mt) * 64 + lq * 8) * 16 + ln;
  // producer word index (in-slot), reg r adds 1:
  const int pidx0 = (((ntb * 16 + ln) * 4 + mt) * 64 + i_me) * 16 + lq * 4;
  const int pidx1 = pidx0 + 16 * 4 * 64 * 16;   // j += 16

  for (int t = 1; t <= 1024; ++t) {
    // prefetch x_t (cacheable loads; hide under poll)
    float xs[2][4];
    if (t < 1024) {
#pragma unroll
      for (int s = 0; s < 2; ++s)
#pragma unroll
        for (int r = 0; r < 4; ++r)
          xs[s][r] = X[(mt * 16 + lq * 4 + r) * 65536 + t * 64 + (ntb + s) * 16 + ln];
    }

    if (t > 1) {
      // ---- poll A_{t-1}: 16 parallel tagged loads until all parity-match ----
      const u32 qm = ((u32)(((t - 1) >> 1) & 1)) << 16;
      u32* sb = wsA + (((t - 1) & 1) << 18);
      u32 W0[8], W1[8];
      int guard = 0;
      for (;;) {
        u32 f0[8], f1[8];
#pragma unroll
        for (int e = 0; e < 8; ++e) {
          f0[e] = ld_agent(sb + cidx0 + e * 16);
          f1[e] = ld_agent(sb + cidx0 + e * 16 + 512);
        }
        u32 bad = 0;
#pragma unroll
        for (int e = 0; e < 8; ++e) {
          bad |= (f0[e] ^ qm) & 0x10000u;
          bad |= (f1[e] ^ qm) & 0x10000u;
        }
        if (!bad || ++guard > (1 << 16)) {
#pragma unroll
          for (int e = 0; e < 8; ++e) { W0[e] = f0[e]; W1[e] = f1[e]; }
          break;
        }
      }

      // ---- y_{t-1}[b, i_me] = sum_k (hi+lo): dot2 with (1,1) + wave reduce ----
      if (!(w & 1)) {
        float ys = 0.f;
#pragma unroll
        for (int e = 0; e < 8; ++e) {
          ys = fdot2_(W0[e], 0x3C003C00u, ys);
          ys = fdot2_(W1[e], 0x3C003C00u, ys);
        }
        ys += __shfl_xor(ys, 16);
        ys += __shfl_xor(ys, 32);
        if (l < 16)
          st_agent((u32*)(Y + (mt * 16 + l) * 65536 + (t - 1) * 64 + i_me),
                   __builtin_bit_cast(u32, ys));
      }

      // ---- A frags: kt0/kt1 = hi halves, kt2/kt3 = lo halves (tag cleared) ----
#pragma unroll
      for (int r = 0; r < 4; ++r) {
        Af[0][r] = __builtin_amdgcn_perm(W0[2 * r + 1], W0[2 * r], 0x05040100u);
        Af[1][r] = __builtin_amdgcn_perm(W1[2 * r + 1], W1[2 * r], 0x05040100u);
        Af[2][r] = __builtin_amdgcn_perm(W0[2 * r + 1], W0[2 * r], 0x07060302u) & 0xFFFEFFFEu;
        Af[3][r] = __builtin_amdgcn_perm(W1[2 * r + 1], W1[2 * r], 0x07060302u) & 0xFFFEFFFEu;
      }
    }

    if (t == 1024) break;   // last iteration only needed y_1023

    // ---- MFMA: C[s] = sum_kt A128[kt] * B128[s][kt] ----
    f16x8 a0 = mk8(Af[0][0], Af[0][1], Af[0][2], Af[0][3]);
    f16x8 a1 = mk8(Af[1][0], Af[1][1], Af[1][2], Af[1][3]);
    f16x8 a2 = mk8(Af[2][0], Af[2][1], Af[2][2], Af[2][3]);
    f16x8 a3 = mk8(Af[3][0], Af[3][1], Af[3][2], Af[3][3]);
    f16x8 b00 = mk8(Bf[0][0][0], Bf[0][0][1], Bf[0][0][2], Bf[0][0][3]);
    f16x8 b01 = mk8(Bf[0][1][0], Bf[0][1][1], Bf[0][1][2], Bf[0][1][3]);
    f16x8 b10 = mk8(Bf[1][0][0], Bf[1][0][1], Bf[1][0][2], Bf[1][0][3]);
    f16x8 b11 = mk8(Bf[1][1][0], Bf[1][1][1], Bf[1][1][2], Bf[1][1][3]);
    f32x4 acc0 = {0.f, 0.f, 0.f, 0.f};
    f32x4 acc1 = {0.f, 0.f, 0.f, 0.f};
    acc0 = __builtin_amdgcn_mfma_f32_16x16x32_f16(a0, b00, acc0, 0, 0, 0);
    acc0 = __builtin_amdgcn_mfma_f32_16x16x32_f16(a1, b01, acc0, 0, 0, 0);
    acc0 = __builtin_amdgcn_mfma_f32_16x16x32_f16(a2, b00, acc0, 0, 0, 0);
    acc0 = __builtin_amdgcn_mfma_f32_16x16x32_f16(a3, b01, acc0, 0, 0, 0);
    acc1 = __builtin_amdgcn_mfma_f32_16x16x32_f16(a0, b10, acc1, 0, 0, 0);
    acc1 = __builtin_amdgcn_mfma_f32_16x16x32_f16(a1, b11, acc1, 0, 0, 0);
    acc1 = __builtin_amdgcn_mfma_f32_16x16x32_f16(a2, b10, acc1, 0, 0, 0);
    acc1 = __builtin_amdgcn_mfma_f32_16x16x32_f16(a3, b11, acc1, 0, 0, 0);

    // ---- publish A_t = x_t * C, tagged ----
    const u32 q = (u32)((t >> 1) & 1);
    u32* sb2 = wsA + ((t & 1) << 18);
#pragma unroll
    for (int r = 0; r < 4; ++r) {
      st_agent(sb2 + pidx0 + r, pack_tag(xs[0][r] * acc0[r], q));
      st_agent(sb2 + pidx1 + r, pack_tag(xs[1][r] * acc1[r], q));
    }
  }
}

extern "C" void kernel_launch(void* const* d_in, const int* in_sizes, int n_in,
                              void* d_out, int out_size, void* d_ws, size_t ws_size,
                              hipStream_t stream) {
  const float* X = (const float*)d_in[0];
  const float* T = (const float*)d_in[1];
  float* Y = (float*)d_out;
  u32* wsA = (u32*)d_ws;   // 2 MB (2 slots x 1 MB)

  prep_kernel<<<2048, 256, 0, stream>>>(X, wsA, Y);
  crf_kernel<<<64, 512, 0, stream>>>(X, T, wsA, Y);
}

// Round 6
// 2692.100 us; speedup vs baseline: 2.1972x; 2.1972x over previous
//
#include <hip/hip_runtime.h>
#include <cstdint>

// CRF2 forward: B=64, S=1024, K=64. i-decomposition with MFMA.
// 64 WGs x 512 thr; WG i owns tag-column i for ALL batches. Per step:
// M[b,i,j] = sum_k A[b,k,i]*T[k,i,j] over 64 batches = GEMM via mfma 16x16x32 f16,
// K extended to 128 (hi/lo f16 state split). Exchange through LLC with per-word
// generation-parity tags; line-coalesced layout; race-fixed with 2 barriers/step.
// Slot word layout: idx = k*4096 + mt*1024 + j*16 + br  (2 slots x 1MB).
//   producer i: k=i, full lines per store instr (dwordx4 sc0 sc1).
//   consumer j: waves split k-halves, swap via LDS.

typedef _Float16 f16;
typedef _Float16 f16x8 __attribute__((ext_vector_type(8)));
typedef float f32x4 __attribute__((ext_vector_type(4)));
typedef unsigned int u32;
typedef unsigned short u16;
typedef u32 u32x4v __attribute__((ext_vector_type(4)));

#define SLOT_WORDS 262144

static __device__ inline void st_agent(u32* p, u32 v) {
  __hip_atomic_store(p, v, __ATOMIC_RELAXED, __HIP_MEMORY_SCOPE_AGENT);
}
static __device__ inline u32 ld_agent(const u32* p) {
  return __hip_atomic_load(p, __ATOMIC_RELAXED, __HIP_MEMORY_SCOPE_AGENT);
}

static __device__ inline float fdot2_(u32 a, u32 b, float c) {
  typedef _Float16 f16x2 __attribute__((ext_vector_type(2)));
  f16x2 av = __builtin_bit_cast(f16x2, a);
  f16x2 bv = __builtin_bit_cast(f16x2, b);
#if __has_builtin(__builtin_amdgcn_fdot2)
  return __builtin_amdgcn_fdot2(av, bv, c, false);
#else
  c = __builtin_fmaf((float)av[0], (float)bv[0], c);
  return __builtin_fmaf((float)av[1], (float)bv[1], c);
#endif
}

// word: hi f16 | (lo f16 with bit0 = generation parity) << 16
static __device__ inline u32 pack_tag(float v, u32 q) {
  f16 h = (f16)v;
  f16 l = (f16)(v - (float)h);
  u32 hb = (u32)__builtin_bit_cast(u16, h);
  u32 lb = (u32)__builtin_bit_cast(u16, l);
  lb = (lb & 0xFFFEu) | q;
  return hb | (lb << 16);
}

static __device__ inline f16x8 mk8(u32 a, u32 b, u32 c, u32 d) {
  u32x4v t = {a, b, c, d};
  return __builtin_bit_cast(f16x8, t);
}

// ---- prep: init wsA parity tags (slot0 tag=0, slot1 tag=1); Y[:,0,:]=X[:,0,:] ----
__global__ void prep_kernel(const float* __restrict__ X, u32* __restrict__ wsA,
                            float* __restrict__ Y) {
  int idx = blockIdx.x * 256 + threadIdx.x;   // 0..524287
  wsA[idx] = (idx >> 18) ? 0x00010000u : 0u;
  if (idx < 4096) {
    int b = idx >> 6, j = idx & 63;
    Y[b * 65536 + j] = X[b * 65536 + j];
  }
}

// ---- main kernel: 64 WGs x 512 threads ----
__global__ __launch_bounds__(512, 1)
void crf_kernel(const float* __restrict__ X, const float* __restrict__ Tg,
                u32* __restrict__ wsA, float* __restrict__ Y) {
  __shared__ u32 Aex[4 * 64 * 17];       // [mt][k][br], pitch 17 (2-way max)
  __shared__ float yph[4][2][16];        // [mt][half][b-row]

  const int i_me = blockIdx.x;
  const int tid  = threadIdx.x;
  const int w    = tid >> 6;
  const int l    = tid & 63;
  const int lq   = l >> 4;
  const int ln   = l & 15;
  const int mt   = w >> 1;               // plane (16-batch group)
  const int h    = w & 1;                // k-half this wave polls; j-half it owns
  const int ntb  = h * 2;                // first n-tile

  // B fragments from global T (f32 -> f16), layout proven in Round 5
  u32 Bf[2][2][4];
#pragma unroll
  for (int s = 0; s < 2; ++s)
#pragma unroll
    for (int kb = 0; kb < 2; ++kb)
#pragma unroll
      for (int r = 0; r < 4; ++r) {
        int k0 = kb * 32 + lq * 8 + 2 * r;
        int j  = (ntb + s) * 16 + ln;
        f16 a = (f16)Tg[k0 * 4096 + i_me * 64 + j];
        f16 b = (f16)Tg[(k0 + 1) * 4096 + i_me * 64 + j];
        Bf[s][kb][r] = (u32)__builtin_bit_cast(u16, a) |
                       ((u32)__builtin_bit_cast(u16, b) << 16);
      }

  // A fragments for t=0: A0[b,k] = x0[b]/64 (constant over k)
  u32 Af[4][4];
  {
    float v = X[(mt * 16 + ln) * 65536 + i_me] * 0.015625f;
    f16 hh = (f16)v; f16 lo = (f16)(v - (float)hh);
    u32 hw = (u32)__builtin_bit_cast(u16, hh);  hw |= hw << 16;
    u32 lw = (u32)__builtin_bit_cast(u16, lo);  lw &= 0xFFFEu; lw |= lw << 16;
#pragma unroll
    for (int r = 0; r < 4; ++r) { Af[0][r] = hw; Af[1][r] = hw; Af[2][r] = lw; Af[3][r] = lw; }
  }

  // consumer base (this wave polls k in [h*32, h*32+32), e adds 4096 words)
  const int cbase = (h * 32 + lq * 8) * 4096 + mt * 1024 + i_me * 16 + ln;
  // producer base (k=i_me; s adds 256 words; r words contiguous -> 16B store)
  const int pbase = (i_me * 4 + mt) * 1024 + ntb * 256 + ln * 16 + lq * 4;

  for (int t = 1; t <= 1024; ++t) {
    // x_t loads (cached; hidden under poll)
    float xs[2][4];
    if (t < 1024) {
#pragma unroll
      for (int s = 0; s < 2; ++s)
#pragma unroll
        for (int r = 0; r < 4; ++r)
          xs[s][r] = X[(mt * 16 + lq * 4 + r) * 65536 + t * 64 + (ntb + s) * 16 + ln];
    }

    u32 W[8];
    if (t > 1) {
      // ---- poll own k-half of A_{t-1} (8 tagged words/lane) ----
      const u32 qm = ((u32)(((t - 1) >> 1) & 1)) << 16;
      const u32* sb = wsA + (((t - 1) & 1) ? SLOT_WORDS : 0);
      int guard = 0;
      for (;;) {
        u32 f[8];
#pragma unroll
        for (int e = 0; e < 8; ++e) f[e] = ld_agent(sb + cbase + e * 4096);
        u32 bad = 0;
#pragma unroll
        for (int e = 0; e < 8; ++e) bad |= (f[e] ^ qm) & 0x10000u;
        if (!bad || ++guard > (1 << 20)) {
#pragma unroll
          for (int e = 0; e < 8; ++e) W[e] = f[e];
          break;
        }
      }
      // y partial over own 32 k's (tag bit contributes ~2^-21 rel: negligible)
      float ys = 0.f;
#pragma unroll
      for (int e = 0; e < 8; ++e) ys = fdot2_(W[e], 0x3C003C00u, ys);
      ys += __shfl_xor(ys, 16);
      ys += __shfl_xor(ys, 32);
      if (l < 16) yph[mt][h][l] = ys;
      // share own half with sibling wave
      if (t < 1024) {
#pragma unroll
        for (int e = 0; e < 8; ++e)
          Aex[(mt * 64 + h * 32 + lq * 8 + e) * 17 + ln] = W[e];
      }
    }

    __syncthreads();   // BAR1: race fix — publish below is gated on ALL waves' polls

    if (t > 1 && h == 0 && l < 16) {
      float yv = yph[mt][0][l] + yph[mt][1][l];
      st_agent((u32*)(Y + (mt * 16 + l) * 65536 + (t - 1) * 64 + i_me),
               __builtin_bit_cast(u32, yv));
    }
    if (t == 1024) break;

    if (t > 1) {
      // read sibling's half, assemble full A-fragments (tag bit cleared in lo)
      u32 V[8];
#pragma unroll
      for (int e = 0; e < 8; ++e)
        V[e] = Aex[(mt * 64 + (1 - h) * 32 + lq * 8 + e) * 17 + ln];
      u32 W0[8], W1[8];
#pragma unroll
      for (int e = 0; e < 8; ++e) { W0[e] = h ? V[e] : W[e]; W1[e] = h ? W[e] : V[e]; }
#pragma unroll
      for (int r = 0; r < 4; ++r) {
        Af[0][r] = __builtin_amdgcn_perm(W0[2 * r + 1], W0[2 * r], 0x05040100u);
        Af[1][r] = __builtin_amdgcn_perm(W1[2 * r + 1], W1[2 * r], 0x05040100u);
        Af[2][r] = __builtin_amdgcn_perm(W0[2 * r + 1], W0[2 * r], 0x07060302u) & 0xFFFEFFFEu;
        Af[3][r] = __builtin_amdgcn_perm(W1[2 * r + 1], W1[2 * r], 0x07060302u) & 0xFFFEFFFEu;
      }
    }

    __syncthreads();   // BAR2: protects Aex/yph reads from next iteration's writes

    // ---- MFMA: C[s] = sum_kt A128 * B128 ----
    f16x8 a0 = mk8(Af[0][0], Af[0][1], Af[0][2], Af[0][3]);
    f16x8 a1 = mk8(Af[1][0], Af[1][1], Af[1][2], Af[1][3]);
    f16x8 a2 = mk8(Af[2][0], Af[2][1], Af[2][2], Af[2][3]);
    f16x8 a3 = mk8(Af[3][0], Af[3][1], Af[3][2], Af[3][3]);
    f16x8 b00 = mk8(Bf[0][0][0], Bf[0][0][1], Bf[0][0][2], Bf[0][0][3]);
    f16x8 b01 = mk8(Bf[0][1][0], Bf[0][1][1], Bf[0][1][2], Bf[0][1][3]);
    f16x8 b10 = mk8(Bf[1][0][0], Bf[1][0][1], Bf[1][0][2], Bf[1][0][3]);
    f16x8 b11 = mk8(Bf[1][1][0], Bf[1][1][1], Bf[1][1][2], Bf[1][1][3]);
    f32x4 acc0 = {0.f, 0.f, 0.f, 0.f};
    f32x4 acc1 = {0.f, 0.f, 0.f, 0.f};
    acc0 = __builtin_amdgcn_mfma_f32_16x16x32_f16(a0, b00, acc0, 0, 0, 0);
    acc0 = __builtin_amdgcn_mfma_f32_16x16x32_f16(a1, b01, acc0, 0, 0, 0);
    acc0 = __builtin_amdgcn_mfma_f32_16x16x32_f16(a2, b00, acc0, 0, 0, 0);
    acc0 = __builtin_amdgcn_mfma_f32_16x16x32_f16(a3, b01, acc0, 0, 0, 0);
    acc1 = __builtin_amdgcn_mfma_f32_16x16x32_f16(a0, b10, acc1, 0, 0, 0);
    acc1 = __builtin_amdgcn_mfma_f32_16x16x32_f16(a1, b11, acc1, 0, 0, 0);
    acc1 = __builtin_amdgcn_mfma_f32_16x16x32_f16(a2, b10, acc1, 0, 0, 0);
    acc1 = __builtin_amdgcn_mfma_f32_16x16x32_f16(a3, b11, acc1, 0, 0, 0);

    // ---- publish A_t: one full-line-coalesced 16B store per n-tile ----
    const u32 q = (u32)((t >> 1) & 1);
    u32* sb2 = wsA + ((t & 1) ? SLOT_WORDS : 0);
    u32x4v d0, d1;
#pragma unroll
    for (int r = 0; r < 4; ++r) {
      d0[r] = pack_tag(xs[0][r] * acc0[r], q);
      d1[r] = pack_tag(xs[1][r] * acc1[r], q);
    }
    u32* p0 = sb2 + pbase;
    u32* p1 = p0 + 256;
    asm volatile("global_store_dwordx4 %0, %1, off sc0 sc1" :: "v"(p0), "v"(d0) : "memory");
    asm volatile("global_store_dwordx4 %0, %1, off sc0 sc1" :: "v"(p1), "v"(d1) : "memory");
  }
}

extern "C" void kernel_launch(void* const* d_in, const int* in_sizes, int n_in,
                              void* d_out, int out_size, void* d_ws, size_t ws_size,
                              hipStream_t stream) {
  const float* X = (const float*)d_in[0];
  const float* T = (const float*)d_in[1];
  float* Y = (float*)d_out;
  u32* wsA = (u32*)d_ws;   // 2 MB (2 slots x 1 MB)

  prep_kernel<<<2048, 256, 0, stream>>>(X, wsA, Y);
  crf_kernel<<<64, 512, 0, stream>>>(X, T, wsA, Y);
}

// Round 7
// 2175.104 us; speedup vs baseline: 2.7195x; 1.2377x over previous
//
#include <hip/hip_runtime.h>
#include <cstdint>

// CRF2 forward: B=64, S=1024, K=64. i-decomposition with MFMA.
// 64 WGs x 512 thr; WG i owns tag-column i for ALL batches. Per step:
// M[b,i,j] = sum_k A[b,k,i]*T[k,i,j] over 64 batches = GEMM via mfma 16x16x32 f16,
// K extended to 128 (hi/lo f16 state split). Exchange through LLC with per-word
// generation-parity tags, full-line-coalesced stores. Minimal critical path:
// poll-all-k per wave (no LDS exchange), ONE barrier per step, publish right
// after MFMA; y-store and x-prefetch pushed after publish.
// Slot word layout: idx = k*4096 + mt*1024 + j*16 + br  (2 slots x 1MB).

typedef _Float16 f16;
typedef _Float16 f16x8 __attribute__((ext_vector_type(8)));
typedef float f32x4 __attribute__((ext_vector_type(4)));
typedef unsigned int u32;
typedef unsigned short u16;
typedef u32 u32x4v __attribute__((ext_vector_type(4)));

#define SLOT_WORDS 262144

static __device__ inline void st_agent(u32* p, u32 v) {
  __hip_atomic_store(p, v, __ATOMIC_RELAXED, __HIP_MEMORY_SCOPE_AGENT);
}
static __device__ inline u32 ld_agent(const u32* p) {
  return __hip_atomic_load(p, __ATOMIC_RELAXED, __HIP_MEMORY_SCOPE_AGENT);
}

static __device__ inline float fdot2_(u32 a, u32 b, float c) {
  typedef _Float16 f16x2 __attribute__((ext_vector_type(2)));
  f16x2 av = __builtin_bit_cast(f16x2, a);
  f16x2 bv = __builtin_bit_cast(f16x2, b);
#if __has_builtin(__builtin_amdgcn_fdot2)
  return __builtin_amdgcn_fdot2(av, bv, c, false);
#else
  c = __builtin_fmaf((float)av[0], (float)bv[0], c);
  return __builtin_fmaf((float)av[1], (float)bv[1], c);
#endif
}

// word: hi f16 | (lo f16 with bit0 = generation parity) << 16
static __device__ inline u32 pack_tag(float v, u32 q) {
  f16 h = (f16)v;
  f16 l = (f16)(v - (float)h);
  u32 hb = (u32)__builtin_bit_cast(u16, h);
  u32 lb = (u32)__builtin_bit_cast(u16, l);
  lb = (lb & 0xFFFEu) | q;
  return hb | (lb << 16);
}

static __device__ inline f16x8 mk8(u32 a, u32 b, u32 c, u32 d) {
  u32x4v t = {a, b, c, d};
  return __builtin_bit_cast(f16x8, t);
}

// ---- prep: init wsA parity tags (slot0 tag=0, slot1 tag=1); Y[:,0,:]=X[:,0,:] ----
__global__ void prep_kernel(const float* __restrict__ X, u32* __restrict__ wsA,
                            float* __restrict__ Y) {
  int idx = blockIdx.x * 256 + threadIdx.x;   // 0..524287
  wsA[idx] = (idx >> 18) ? 0x00010000u : 0u;
  if (idx < 4096) {
    int b = idx >> 6, j = idx & 63;
    Y[b * 65536 + j] = X[b * 65536 + j];
  }
}

// ---- main kernel: 64 WGs x 512 threads, no LDS, 1 barrier/step ----
__global__ __launch_bounds__(512, 1)
void crf_kernel(const float* __restrict__ X, const float* __restrict__ Tg,
                u32* __restrict__ wsA, float* __restrict__ Y) {
  const int i_me = blockIdx.x;
  const int tid  = threadIdx.x;
  const int w    = tid >> 6;
  const int l    = tid & 63;
  const int lq   = l >> 4;
  const int ln   = l & 15;
  const int mt   = w >> 1;               // plane (16-batch group)
  const int h    = w & 1;                // j-half this wave publishes
  const int ntb  = h * 2;                // first n-tile

  // B fragments from global T (f32 -> f16); layout proven in rounds 5/6
  u32 Bf[2][2][4];
#pragma unroll
  for (int s = 0; s < 2; ++s)
#pragma unroll
    for (int kb = 0; kb < 2; ++kb)
#pragma unroll
      for (int r = 0; r < 4; ++r) {
        int k0 = kb * 32 + lq * 8 + 2 * r;
        int j  = (ntb + s) * 16 + ln;
        f16 a = (f16)Tg[k0 * 4096 + i_me * 64 + j];
        f16 b = (f16)Tg[(k0 + 1) * 4096 + i_me * 64 + j];
        Bf[s][kb][r] = (u32)__builtin_bit_cast(u16, a) |
                       ((u32)__builtin_bit_cast(u16, b) << 16);
      }

  // A fragments for t=0: A0[b,k] = x0[b]/64 (constant over k)
  u32 Af[4][4];
  {
    float v = X[(mt * 16 + ln) * 65536 + i_me] * 0.015625f;
    f16 hh = (f16)v; f16 lo = (f16)(v - (float)hh);
    u32 hw = (u32)__builtin_bit_cast(u16, hh);  hw |= hw << 16;
    u32 lw = (u32)__builtin_bit_cast(u16, lo);  lw &= 0xFFFEu; lw |= lw << 16;
#pragma unroll
    for (int r = 0; r < 4; ++r) { Af[0][r] = hw; Af[1][r] = hw; Af[2][r] = lw; Af[3][r] = lw; }
  }

  // consumer base: word (k = lq*8 + e, mt, j = i_me, br = ln); +131072 for k+=32
  const int cbase = (lq * 8) * 4096 + mt * 1024 + i_me * 16 + ln;
  // producer base (k = i_me): full 64B lines per dwordx4 pair
  const int pbase = (i_me * 4 + mt) * 1024 + ntb * 256 + ln * 16 + lq * 4;

  // preload x for t=1
  float xs[2][4];
#pragma unroll
  for (int s = 0; s < 2; ++s)
#pragma unroll
    for (int r = 0; r < 4; ++r)
      xs[s][r] = X[(mt * 16 + lq * 4 + r) * 65536 + 64 + (ntb + s) * 16 + ln];

  for (int t = 1; t <= 1024; ++t) {
    u32 W0[8], W1[8];
    if (t > 1) {
      // ---- poll ALL 64 k for (mt, j=i_me): 16 tagged words/lane ----
      const u32 qm = ((u32)(((t - 1) >> 1) & 1)) << 16;
      const u32* sb = wsA + (((t - 1) & 1) ? SLOT_WORDS : 0);
      int guard = 0;
      for (;;) {
        u32 f0[8], f1[8];
#pragma unroll
        for (int e = 0; e < 8; ++e) {
          f0[e] = ld_agent(sb + cbase + e * 4096);
          f1[e] = ld_agent(sb + cbase + e * 4096 + 131072);
        }
        u32 bad = 0;
#pragma unroll
        for (int e = 0; e < 8; ++e) {
          bad |= (f0[e] ^ qm) & 0x10000u;
          bad |= (f1[e] ^ qm) & 0x10000u;
        }
        if (!bad || ++guard > (1 << 20)) {
#pragma unroll
          for (int e = 0; e < 8; ++e) { W0[e] = f0[e]; W1[e] = f1[e]; }
          break;
        }
      }
    }

    // BAR: all waves of this WG finished reading slot (t-1)&1 == slot t&1's
    // previous generation -> safe to overwrite below (2-hop chain, rounds 5/6)
    __syncthreads();

    if (t > 1) {
      // assemble A-frags: kt0/kt1 hi halves, kt2/kt3 lo halves (tag cleared)
#pragma unroll
      for (int r = 0; r < 4; ++r) {
        Af[0][r] = __builtin_amdgcn_perm(W0[2 * r + 1], W0[2 * r], 0x05040100u);
        Af[1][r] = __builtin_amdgcn_perm(W1[2 * r + 1], W1[2 * r], 0x05040100u);
        Af[2][r] = __builtin_amdgcn_perm(W0[2 * r + 1], W0[2 * r], 0x07060302u) & 0xFFFEFFFEu;
        Af[3][r] = __builtin_amdgcn_perm(W1[2 * r + 1], W1[2 * r], 0x07060302u) & 0xFFFEFFFEu;
      }
    }

    if (t < 1024) {
      // ---- MFMA + immediate publish (critical path) ----
      f16x8 a0 = mk8(Af[0][0], Af[0][1], Af[0][2], Af[0][3]);
      f16x8 a1 = mk8(Af[1][0], Af[1][1], Af[1][2], Af[1][3]);
      f16x8 a2 = mk8(Af[2][0], Af[2][1], Af[2][2], Af[2][3]);
      f16x8 a3 = mk8(Af[3][0], Af[3][1], Af[3][2], Af[3][3]);
      f16x8 b00 = mk8(Bf[0][0][0], Bf[0][0][1], Bf[0][0][2], Bf[0][0][3]);
      f16x8 b01 = mk8(Bf[0][1][0], Bf[0][1][1], Bf[0][1][2], Bf[0][1][3]);
      f16x8 b10 = mk8(Bf[1][0][0], Bf[1][0][1], Bf[1][0][2], Bf[1][0][3]);
      f16x8 b11 = mk8(Bf[1][1][0], Bf[1][1][1], Bf[1][1][2], Bf[1][1][3]);
      f32x4 acc0 = {0.f, 0.f, 0.f, 0.f};
      f32x4 acc1 = {0.f, 0.f, 0.f, 0.f};
      acc0 = __builtin_amdgcn_mfma_f32_16x16x32_f16(a0, b00, acc0, 0, 0, 0);
      acc0 = __builtin_amdgcn_mfma_f32_16x16x32_f16(a1, b01, acc0, 0, 0, 0);
      acc0 = __builtin_amdgcn_mfma_f32_16x16x32_f16(a2, b00, acc0, 0, 0, 0);
      acc0 = __builtin_amdgcn_mfma_f32_16x16x32_f16(a3, b01, acc0, 0, 0, 0);
      acc1 = __builtin_amdgcn_mfma_f32_16x16x32_f16(a0, b10, acc1, 0, 0, 0);
      acc1 = __builtin_amdgcn_mfma_f32_16x16x32_f16(a1, b11, acc1, 0, 0, 0);
      acc1 = __builtin_amdgcn_mfma_f32_16x16x32_f16(a2, b10, acc1, 0, 0, 0);
      acc1 = __builtin_amdgcn_mfma_f32_16x16x32_f16(a3, b11, acc1, 0, 0, 0);

      const u32 q = (u32)((t >> 1) & 1);
      u32* sb2 = wsA + ((t & 1) ? SLOT_WORDS : 0);
      u32x4v d0, d1;
#pragma unroll
      for (int r = 0; r < 4; ++r) {
        d0[r] = pack_tag(xs[0][r] * acc0[r], q);
        d1[r] = pack_tag(xs[1][r] * acc1[r], q);
      }
      u32* p0 = sb2 + pbase;
      u32* p1 = p0 + 256;
      asm volatile("global_store_dwordx4 %0, %1, off sc0 sc1" :: "v"(p0), "v"(d0) : "memory");
      asm volatile("global_store_dwordx4 %0, %1, off sc0 sc1" :: "v"(p1), "v"(d1) : "memory");
    }

    // ---- off-critical-path: y_{t-1} and x prefetch for t+1 ----
    if (t > 1) {
      float ys = 0.f;
#pragma unroll
      for (int e = 0; e < 8; ++e) {
        ys = fdot2_(W0[e], 0x3C003C00u, ys);
        ys = fdot2_(W1[e], 0x3C003C00u, ys);
      }
      ys += __shfl_xor(ys, 16);
      ys += __shfl_xor(ys, 32);
      if (h == 0 && l < 16)
        Y[(mt * 16 + l) * 65536 + (t - 1) * 64 + i_me] = ys;
    }
    if (t < 1023) {
#pragma unroll
      for (int s = 0; s < 2; ++s)
#pragma unroll
        for (int r = 0; r < 4; ++r)
          xs[s][r] = X[(mt * 16 + lq * 4 + r) * 65536 + (t + 1) * 64 + (ntb + s) * 16 + ln];
    }
  }
}

extern "C" void kernel_launch(void* const* d_in, const int* in_sizes, int n_in,
                              void* d_out, int out_size, void* d_ws, size_t ws_size,
                              hipStream_t stream) {
  const float* X = (const float*)d_in[0];
  const float* T = (const float*)d_in[1];
  float* Y = (float*)d_out;
  u32* wsA = (u32*)d_ws;   // 2 MB (2 slots x 1 MB)

  prep_kernel<<<2048, 256, 0, stream>>>(X, wsA, Y);
  crf_kernel<<<64, 512, 0, stream>>>(X, T, wsA, Y);
}